// Round 7
// baseline (2214.707 us; speedup 1.0000x reference)
//
#include <hip/hip_runtime.h>

#define DI __device__ __forceinline__

typedef __attribute__((ext_vector_type(4))) float f32x4;
typedef __attribute__((ext_vector_type(8))) short short8;
typedef __attribute__((ext_vector_type(4))) short s16x4;
typedef __attribute__((ext_vector_type(4))) unsigned u32x4;
typedef unsigned short u16;
typedef unsigned long long u64;

#define GLDS(gp, lp)                                              \
  __builtin_amdgcn_global_load_lds(                               \
      (const __attribute__((address_space(1))) void*)(gp),        \
      (__attribute__((address_space(3))) void*)(lp), 16, 0, 0)

DI u16 f2bf(float f) {
  unsigned u = __builtin_bit_cast(unsigned, f);
  u += 0x7fffu + ((u >> 16) & 1u);
  return (u16)(u >> 16);
}
DI float bf2f(u16 h) {
  unsigned u = ((unsigned)h) << 16;
  return __builtin_bit_cast(float, u);
}
DI unsigned cvtpk(float lo, float hi) {
  unsigned r;
  asm("v_cvt_pk_bf16_f32 %0, %1, %2" : "=v"(r) : "v"(lo), "v"(hi));
  return r;
}

// ---------------------------------------------------------------------------
// GEMM: C = epilogue(A[.,lda] * B[.,ldb]^T). A bf16 via global_load_lds
// (linear LDS dest, inverse-swizzled source); B fp32 reg-staged ->
// v_cvt_pk_bf16_f32 -> swizzled ds_write_b128. Double-buffered, one
// __syncthreads per K-step. K-slice offset = z*kz (split-K).
// MODE 0: fp32 out = acc (split-K partial)   -> Cp + z*sC + m*N + n
// MODE 1: bf16 out = relu(acc + bias[n])     -> Cp + m*N + n
// MODE 2: fused QKV: z selects A (q vs kv), W (Bp/Bp2/Bp3), dest:
//         z=0 -> q scatter, z=1 -> k scatter [((b*16+h)*1024+t)*64+d],
//         z=2 -> V^T direct: LDS-transposed epilogue -> vt[bh][d][1024 t]
// ---------------------------------------------------------------------------
template <int MODE>
__global__ __launch_bounds__(256, 2) void gemm_bt(
    const u16* __restrict__ Ap, const u16* __restrict__ Ap2,
    const float* __restrict__ Bp, const float* __restrict__ Bp2,
    const float* __restrict__ Bp3, void* __restrict__ Cp,
    void* __restrict__ Cp2, void* __restrict__ Cp3,
    const float* __restrict__ bias, int N, int lda, int ldb, int kz, int NT,
    long sC, float scale) {
  constexpr int BM = 128, BN = 128;
  constexpr int WM = BM / 2, WN = BN / 2, FM = WM / 16, FN = WN / 16;
  constexpr int ATILE = BM * 128, TILE = ATILE + BN * 128;

  __shared__ char smem[2 * TILE];

  const int tid = threadIdx.x;
  const int wid = tid >> 6, lane = tid & 63;
  const int z = blockIdx.z;
  const long bm = (long)blockIdx.y * BM;
  const long bn = (long)blockIdx.x * BN;
  const int kofs = z * kz;

  const u16* A16 = (MODE == 2 && z > 0) ? Ap2 : Ap;
  const float* Bw = (MODE == 2) ? (z == 0 ? Bp : (z == 1 ? Bp2 : Bp3)) : Bp;

  // A staging: GLDS, 8 rows x 8 slots per 1KB chunk, source pre-swizzled
  const int lrow = lane >> 3;
  const int lslot = (lane & 7) ^ lrow;
  const u16* asrc0 = A16 + (bm + lrow) * (long)lda + kofs + lslot * 8;

  auto stageA = [&](int kt, char* buf) {
    const u16* as = asrc0 + kt * 64;
#pragma unroll
    for (int c = 0; c < 4; c++) {
      int chunk = wid * 4 + c;
      GLDS(as + (long)chunk * 8 * lda, buf + chunk * 1024);
    }
  };

  // B staging: fp32 regs -> cvt_pk -> swizzled LDS
  const int rowB = tid >> 1, colB = (tid & 1) * 32;
  const float* bsrc0 = Bw + (bn + rowB) * (long)ldb + kofs + colB;
  float fb[32];

  auto loadB = [&](int kt) {
    const float* p = bsrc0 + kt * 64;
#pragma unroll
    for (int i = 0; i < 8; i++) {
      f32x4 v = *(const f32x4*)(p + i * 4);
#pragma unroll
      for (int e = 0; e < 4; e++) fb[i * 4 + e] = v[e];
    }
  };
  auto writeB = [&](char* buf) {
    char* Bs = buf + ATILE;
#pragma unroll
    for (int c = 0; c < 4; c++) {
      u32x4 w;
#pragma unroll
      for (int e = 0; e < 4; e++)
        w[e] = cvtpk(fb[c * 8 + e * 2], fb[c * 8 + e * 2 + 1]);
      int byte = rowB * 128 + (colB + c * 8) * 2;
      byte ^= (rowB & 7) << 4;
      *(u32x4*)(Bs + byte) = w;
    }
  };

  const int wm = wid >> 1, wn = wid & 1;
  const int l15 = lane & 15, ks = lane >> 4;

  f32x4 acc[FM][FN];
#pragma unroll
  for (int i = 0; i < FM; i++)
#pragma unroll
    for (int j = 0; j < FN; j++) acc[i][j] = (f32x4){0.f, 0.f, 0.f, 0.f};

  auto compute = [&](const char* buf) {
    const char* As = buf;
    const char* Bs = buf + ATILE;
#pragma unroll
    for (int kk = 0; kk < 2; kk++) {
      short8 af[FM], bfr[FN];
#pragma unroll
      for (int i = 0; i < FM; i++) {
        int row = wm * WM + i * 16 + l15;
        int byte = row * 128 + kk * 64 + ks * 16;
        byte ^= (row & 7) << 4;
        af[i] = *(const short8*)(As + byte);
      }
#pragma unroll
      for (int j = 0; j < FN; j++) {
        int row = wn * WN + j * 16 + l15;
        int byte = row * 128 + kk * 64 + ks * 16;
        byte ^= (row & 7) << 4;
        bfr[j] = *(const short8*)(Bs + byte);
      }
#pragma unroll
      for (int i = 0; i < FM; i++)
#pragma unroll
        for (int j = 0; j < FN; j++)
          acc[i][j] = __builtin_amdgcn_mfma_f32_16x16x32_bf16(af[i], bfr[j],
                                                              acc[i][j], 0, 0, 0);
    }
  };

  loadB(0);
  stageA(0, smem);
  writeB(smem);
  __syncthreads();
  for (int t = 0; t < NT; ++t) {
    char* cur = smem + (t & 1) * TILE;
    char* nxt = smem + ((t + 1) & 1) * TILE;
    if (t + 1 < NT) { loadB(t + 1); stageA(t + 1, nxt); }
    compute(cur);
    if (t + 1 < NT) writeB(nxt);
    __syncthreads();
  }

  if constexpr (MODE == 2) {
    if (z == 2) {
      // V^T epilogue: acc -> LDS transposed [n'][b*64+t'] -> coalesced vt
      char* tb = smem;
#pragma unroll
      for (int i = 0; i < FM; i++) {
#pragma unroll
        for (int j = 0; j < FN; j++) {
          int np = wn * 64 + j * 16 + l15;
          int basem = wm * 64 + i * 16 + ks * 4;
          unsigned lo = (unsigned)f2bf(acc[i][j][0]) |
                        ((unsigned)f2bf(acc[i][j][2]) << 16);
          unsigned hi = (unsigned)f2bf(acc[i][j][1]) |
                        ((unsigned)f2bf(acc[i][j][3]) << 16);
          int byte0 = np * 256 + basem;
          int byte1 = np * 256 + 128 + basem;
          byte0 ^= (np & 7) << 4;
          byte1 ^= (np & 7) << 4;
          *(unsigned*)(tb + byte0) = lo;
          *(unsigned*)(tb + byte1) = hi;
        }
      }
      __syncthreads();
      const int np = tid >> 1, bsel = tid & 1;
      const int h_ = (int)((bn + np) >> 6), d_ = (int)((bn + np) & 63);
      u16* dst = (u16*)Cp3 + ((long)(bsel * 16 + h_) * 64 + d_) * 1024 +
                 (bm >> 1);
#pragma unroll
      for (int c = 0; c < 8; c++) {
        int byte = np * 256 + bsel * 128 + c * 16;
        byte ^= (np & 7) << 4;
        *(short8*)(dst + c * 8) = *(const short8*)(tb + byte);
      }
      return;
    }
  }

  const float scl = (MODE == 2 && z > 0) ? 1.f : scale;
#pragma unroll
  for (int i = 0; i < FM; i++) {
#pragma unroll
    for (int j = 0; j < FN; j++) {
#pragma unroll
      for (int r = 0; r < 4; r++) {
        long m = bm + wm * WM + i * 16 + ks * 4 + r;
        long n = bn + wn * WN + j * 16 + l15;
        float val = acc[i][j][r] * scl;
        if constexpr (MODE == 0) {
          ((float*)Cp)[z * sC + m * (long)N + n] = val;
        } else if constexpr (MODE == 1) {
          val += bias[n];
          ((u16*)Cp)[m * (long)N + n] = f2bf(fmaxf(val, 0.f));
        } else if constexpr (MODE == 2) {
          u16* Cz = (u16*)(z == 0 ? Cp : Cp2);
          long t_ = m >> 1;
          int b_ = (int)(m & 1), h_ = (int)(n >> 6), d_ = (int)(n & 63);
          Cz[(((long)(b_ * 16 + h_) * 1024 + t_) << 6) + d_] = f2bf(val);
        }
      }
    }
  }
}

// ---------------------------------------------------------------------------
// Flash attention: block = 64 q rows x one (b,h); 4 waves x 16 q rows.
// K/V tiles (KVBLK=64) staged in block-shared LDS via global_load_lds,
// double-buffered, one barrier per tile. P staging is wave-local LDS.
// ---------------------------------------------------------------------------
__global__ __launch_bounds__(256, 2) void flash_k(
    const u16* __restrict__ q, const u16* __restrict__ kb,
    const u16* __restrict__ vt, u16* __restrict__ ab) {
  __shared__ char Ks[2][8192];       // [kv 64][d 64] bf16, XOR-swizzled
  __shared__ char Vs[2][8192];       // [d 64][kv 64] bf16, XOR-swizzled
  __shared__ char P_lds[4][2048];    // per wave: 16 q x 64 kv bf16
  __shared__ float stats[4][16];

  const int tid = threadIdx.x;
  const int wid = tid >> 6, lane = tid & 63;
  const int l15 = lane & 15, ks = lane >> 4;
  const int z = blockIdx.y;
  const int q0 = blockIdx.x * 64 + wid * 16;

  const u16* Qz = q + (long)z * 65536;
  const u16* Kz = kb + (long)z * 65536;
  const u16* Vz = vt + (long)z * 65536;
  char* Pw = P_lds[wid];
  float* st = stats[wid];

  const int r_l = lane >> 3;
  const int swsl = ((lane & 7) ^ r_l) * 8;

  auto stageKV = [&](int t, int buf) {
    const int kv0 = t * 64;
#pragma unroll
    for (int c = 0; c < 2; c++) {
      int chunk = wid * 2 + c;
      GLDS(Kz + (long)(kv0 + chunk * 8 + r_l) * 64 + swsl,
           Ks[buf] + chunk * 1024);
      GLDS(Vz + (long)(chunk * 8 + r_l) * 1024 + kv0 + swsl,
           Vs[buf] + chunk * 1024);
    }
  };

  short8 qf[2];
#pragma unroll
  for (int kk = 0; kk < 2; kk++)
    qf[kk] = *(const short8*)(Qz + (q0 + l15) * 64 + kk * 32 + ks * 8);

  f32x4 Oacc[4];
#pragma unroll
  for (int nf = 0; nf < 4; nf++) Oacc[nf] = (f32x4){0.f, 0.f, 0.f, 0.f};
  float mrun = -1e30f, lrun = 0.f;

  stageKV(0, 0);
  __syncthreads();
  for (int t = 0; t < 16; ++t) {
    const int cur = t & 1;
    if (t + 1 < 16) stageKV(t + 1, cur ^ 1);
    f32x4 s[4];
#pragma unroll
    for (int m = 0; m < 4; m++) s[m] = (f32x4){0.f, 0.f, 0.f, 0.f};
#pragma unroll
    for (int kk = 0; kk < 2; kk++) {
#pragma unroll
      for (int m = 0; m < 4; m++) {
        int row = m * 16 + l15;
        int byte = row * 128 + kk * 64 + ks * 16;
        byte ^= (row & 7) << 4;
        short8 kf = *(const short8*)(Ks[cur] + byte);
        s[m] = __builtin_amdgcn_mfma_f32_16x16x32_bf16(kf, qf[kk], s[m], 0, 0, 0);
      }
    }
    float tmax = s[0][0];
#pragma unroll
    for (int m = 0; m < 4; m++)
#pragma unroll
      for (int r = 0; r < 4; r++) tmax = fmaxf(tmax, s[m][r]);
    tmax = fmaxf(tmax, __shfl_xor(tmax, 16));
    tmax = fmaxf(tmax, __shfl_xor(tmax, 32));
    const float mnew = fmaxf(mrun, tmax);
    const float factor = __expf(mrun - mnew);
    float psum = 0.f;
#pragma unroll
    for (int m = 0; m < 4; m++) {
      u16 p4[4];
#pragma unroll
      for (int r = 0; r < 4; r++) {
        float e = __expf(s[m][r] - mnew);
        psum += e;
        p4[r] = f2bf(e);
      }
      u64 pk = (u64)p4[0] | ((u64)p4[1] << 16) | ((u64)p4[2] << 32) |
               ((u64)p4[3] << 48);
      int byte = l15 * 128 + m * 32 + ks * 8;
      byte ^= (l15 & 7) << 4;
      *(u64*)(Pw + byte) = pk;
    }
    psum += __shfl_xor(psum, 16);
    psum += __shfl_xor(psum, 32);
    lrun = lrun * factor + psum;
    mrun = mnew;
    if (ks == 0) st[l15] = factor;
    f32x4 facv = *(const f32x4*)&st[ks * 4];
#pragma unroll
    for (int nf = 0; nf < 4; nf++)
#pragma unroll
      for (int r = 0; r < 4; r++) Oacc[nf][r] *= facv[r];
#pragma unroll
    for (int kk = 0; kk < 2; kk++) {
      int pb = l15 * 128 + kk * 64 + ks * 16;
      pb ^= (l15 & 7) << 4;
      short8 pa = *(const short8*)(Pw + pb);
#pragma unroll
      for (int nf = 0; nf < 4; nf++) {
        int row = nf * 16 + l15;
        int vb_ = row * 128 + kk * 64 + ks * 16;
        vb_ ^= (row & 7) << 4;
        short8 vf = *(const short8*)(Vs[cur] + vb_);
        Oacc[nf] = __builtin_amdgcn_mfma_f32_16x16x32_bf16(pa, vf, Oacc[nf],
                                                           0, 0, 0);
      }
    }
    __syncthreads();
  }
  if (ks == 0) st[l15] = 1.f / lrun;
  f32x4 invv = *(const f32x4*)&st[ks * 4];
  const int b_ = z >> 4, h_ = z & 15;
#pragma unroll
  for (int nf = 0; nf < 4; nf++) {
#pragma unroll
    for (int r = 0; r < 4; r++) {
      int qg = q0 + ks * 4 + r;
      ab[((long)(qg * 2 + b_) << 10) + h_ * 64 + nf * 16 + l15] =
          f2bf(Oacc[nf][r] * invv[r]);
    }
  }
}

// ---------------------------------------------------------------------------
// out = LN(x + sum(parts) + cb) * g + b ; writes fp32 out and optional bf16
// ---------------------------------------------------------------------------
template <int NP>
__global__ __launch_bounds__(256) void add_ln_k(
    const float* __restrict__ x, const float* __restrict__ parts,
    const float* __restrict__ cb, const float* __restrict__ g,
    const float* __restrict__ b, float* __restrict__ out,
    u16* __restrict__ outh) {
  const long row = blockIdx.x;
  const int tid = threadIdx.x;
  const long base = row * 1024 + tid * 4;
  f32x4 v = *(const f32x4*)(x + base);
#pragma unroll
  for (int p = 0; p < NP; p++) {
    f32x4 q = *(const f32x4*)(parts + (long)p * 2048 * 1024 + base);
    v[0] += q[0]; v[1] += q[1]; v[2] += q[2]; v[3] += q[3];
  }
  if (cb) {
    f32x4 q = *(const f32x4*)(cb + tid * 4);
    v[0] += q[0]; v[1] += q[1]; v[2] += q[2]; v[3] += q[3];
  }
  float s = v[0] + v[1] + v[2] + v[3];
  float s2 = v[0] * v[0] + v[1] * v[1] + v[2] * v[2] + v[3] * v[3];
#pragma unroll
  for (int off = 1; off < 64; off <<= 1) {
    s += __shfl_xor(s, off);
    s2 += __shfl_xor(s2, off);
  }
  __shared__ float ps[8];
  const int wid = tid >> 6, lane = tid & 63;
  if (lane == 0) {
    ps[wid] = s;
    ps[4 + wid] = s2;
  }
  __syncthreads();
  s = ps[0] + ps[1] + ps[2] + ps[3];
  s2 = ps[4] + ps[5] + ps[6] + ps[7];
  float mean = s * (1.f / 1024.f);
  float var = s2 * (1.f / 1024.f) - mean * mean;
  float rstd = rsqrtf(var + 1e-5f);
  f32x4 gg = *(const f32x4*)(g + tid * 4);
  f32x4 bb = *(const f32x4*)(b + tid * 4);
  f32x4 o;
#pragma unroll
  for (int j = 0; j < 4; j++) o[j] = (v[j] - mean) * rstd * gg[j] + bb[j];
  *(f32x4*)(out + base) = o;
  if (outh) {
    s16x4 hh;
#pragma unroll
    for (int j = 0; j < 4; j++) hh[j] = (short)f2bf(o[j]);
    *(s16x4*)(outh + base) = hh;
  }
}

// fp32 -> (fp32 copy, bf16 copy)
__global__ __launch_bounds__(256) void cast_k(const float* __restrict__ in,
                                              float* __restrict__ o32,
                                              u16* __restrict__ o16) {
  const long i = ((long)blockIdx.x * 256 + threadIdx.x) * 4;
  f32x4 v = *(const f32x4*)(in + i);
  *(f32x4*)(o32 + i) = v;
  s16x4 hh;
#pragma unroll
  for (int j = 0; j < 4; j++) hh[j] = (short)f2bf(v[j]);
  *(s16x4*)(o16 + i) = hh;
}

// ---------------------------------------------------------------------------
extern "C" void kernel_launch(void* const* d_in, const int* in_sizes, int n_in,
                              void* d_out, int out_size, void* d_ws,
                              size_t ws_size, hipStream_t stream) {
  const float* src = (const float*)d_in[0];
  const float* tgt = (const float*)d_in[1];
  const float* enc_Wq = (const float*)d_in[2];
  const float* enc_Wk = (const float*)d_in[3];
  const float* enc_Wv = (const float*)d_in[4];
  const float* enc_Wo = (const float*)d_in[5];
  const float* enc_bo = (const float*)d_in[6];
  const float* enc_ln1_g = (const float*)d_in[7];
  const float* enc_ln1_b = (const float*)d_in[8];
  const float* enc_W1 = (const float*)d_in[9];
  const float* enc_b1 = (const float*)d_in[10];
  const float* enc_W2 = (const float*)d_in[11];
  const float* enc_b2 = (const float*)d_in[12];
  const float* enc_ln2_g = (const float*)d_in[13];
  const float* enc_ln2_b = (const float*)d_in[14];
  const float* enc_fn_g = (const float*)d_in[15];
  const float* enc_fn_b = (const float*)d_in[16];
  const float* dec_sWq = (const float*)d_in[17];
  const float* dec_sWk = (const float*)d_in[18];
  const float* dec_sWv = (const float*)d_in[19];
  const float* dec_sWo = (const float*)d_in[20];
  const float* dec_sbo = (const float*)d_in[21];
  const float* dec_ln1_g = (const float*)d_in[22];
  const float* dec_ln1_b = (const float*)d_in[23];
  const float* dec_cWq = (const float*)d_in[24];
  const float* dec_cWk = (const float*)d_in[25];
  const float* dec_cWv = (const float*)d_in[26];
  const float* dec_cWo = (const float*)d_in[27];
  const float* dec_cbo = (const float*)d_in[28];
  const float* dec_ln2_g = (const float*)d_in[29];
  const float* dec_ln2_b = (const float*)d_in[30];
  const float* dec_W1 = (const float*)d_in[31];
  const float* dec_b1 = (const float*)d_in[32];
  const float* dec_W2 = (const float*)d_in[33];
  const float* dec_b2 = (const float*)d_in[34];
  const float* dec_ln3_g = (const float*)d_in[35];
  const float* dec_ln3_b = (const float*)d_in[36];
  const float* dec_fn_g = (const float*)d_in[37];
  const float* dec_fn_b = (const float*)d_in[38];

  char* ws = (char*)d_ws;
  size_t off = 0;
  auto alloc = [&](size_t bytes) {
    void* p = ws + off;
    off += (bytes + 255) & ~(size_t)255;
    return p;
  };
  float* xf = (float*)alloc(2048L * 1024 * 4);
  float* mem = (float*)alloc(2048L * 1024 * 4);
  u16* xh = (u16*)alloc(2048L * 1024 * 2);
  u16* memh = (u16*)alloc(2048L * 1024 * 2);
  u16* h = (u16*)alloc(2048L * 4096 * 2);
  u16* q = (u16*)alloc(2048L * 1024 * 2);
  u16* kb = (u16*)alloc(2048L * 1024 * 2);
  u16* vt = (u16*)alloc(2048L * 1024 * 2);
  u16* ab = (u16*)alloc(2048L * 1024 * 2);
  float* parts = (float*)alloc(4L * 2048 * 1024 * 4);

  const long sP = 2048L * 1024;

  auto attn = [&](const u16* qin, const u16* kvin, const float* Wq,
                  const float* Wk, const float* Wv, const float* Wo) {
    // fused QKV projection (z: 0=Q, 1=K, 2=V^T-direct)
    gemm_bt<2><<<dim3(8, 16, 3), 256, 0, stream>>>(
        qin, kvin, Wq, Wk, Wv, q, kb, vt, nullptr,
        1024, 1024, 1024, 0, 16, 0, 0.125f);
    flash_k<<<dim3(16, 32), 256, 0, stream>>>(q, kb, vt, ab);
    // O projection, split-K=2 -> fp32 partials
    gemm_bt<0><<<dim3(8, 16, 2), 256, 0, stream>>>(
        ab, nullptr, Wo, nullptr, nullptr, parts, nullptr, nullptr, nullptr,
        1024, 1024, 1024, 512, 8, sP, 1.f);
  };
  auto ffn = [&](const u16* xin, const float* W1, const float* b1,
                 const float* W2) {
    gemm_bt<1><<<dim3(32, 16, 1), 256, 0, stream>>>(
        xin, nullptr, W1, nullptr, nullptr, h, nullptr, nullptr, b1,
        4096, 1024, 1024, 0, 16, 0, 1.f);
    // FFN2 split-K=4 -> fp32 partials
    gemm_bt<0><<<dim3(8, 16, 4), 256, 0, stream>>>(
        h, nullptr, W2, nullptr, nullptr, parts, nullptr, nullptr, nullptr,
        1024, 4096, 4096, 1024, 16, sP, 1.f);
  };

  const long DD = 1024L * 1024, Dv = 1024, FFD = 4096L * 1024, FFv = 4096;

  cast_k<<<dim3(2048), 256, 0, stream>>>(src, xf, xh);
  for (int i = 0; i < 4; i++) {
    attn(xh, xh, enc_Wq + i * DD, enc_Wk + i * DD, enc_Wv + i * DD,
         enc_Wo + i * DD);
    add_ln_k<2><<<dim3(2048), 256, 0, stream>>>(
        xf, parts, enc_bo + i * Dv, enc_ln1_g + i * Dv, enc_ln1_b + i * Dv,
        xf, xh);
    ffn(xh, enc_W1 + i * FFD, enc_b1 + i * FFv, enc_W2 + i * FFD);
    add_ln_k<4><<<dim3(2048), 256, 0, stream>>>(
        xf, parts, enc_b2 + i * Dv, enc_ln2_g + i * Dv, enc_ln2_b + i * Dv,
        xf, xh);
  }
  add_ln_k<0><<<dim3(2048), 256, 0, stream>>>(
      xf, nullptr, nullptr, enc_fn_g, enc_fn_b, mem, memh);

  cast_k<<<dim3(2048), 256, 0, stream>>>(tgt, xf, xh);
  for (int i = 0; i < 4; i++) {
    attn(xh, xh, dec_sWq + i * DD, dec_sWk + i * DD, dec_sWv + i * DD,
         dec_sWo + i * DD);
    add_ln_k<2><<<dim3(2048), 256, 0, stream>>>(
        xf, parts, dec_sbo + i * Dv, dec_ln1_g + i * Dv, dec_ln1_b + i * Dv,
        xf, xh);
    attn(xh, memh, dec_cWq + i * DD, dec_cWk + i * DD, dec_cWv + i * DD,
         dec_cWo + i * DD);
    add_ln_k<2><<<dim3(2048), 256, 0, stream>>>(
        xf, parts, dec_cbo + i * Dv, dec_ln2_g + i * Dv, dec_ln2_b + i * Dv,
        xf, xh);
    ffn(xh, dec_W1 + i * FFD, dec_b1 + i * FFv, dec_W2 + i * FFD);
    add_ln_k<4><<<dim3(2048), 256, 0, stream>>>(
        xf, parts, dec_b2 + i * Dv, dec_ln3_g + i * Dv, dec_ln3_b + i * Dv,
        xf, xh);
  }
  add_ln_k<0><<<dim3(2048), 256, 0, stream>>>(
      xf, nullptr, nullptr, dec_fn_g, dec_fn_b, (float*)d_out, nullptr);
}

// Round 8
// 1475.978 us; speedup vs baseline: 1.5005x; 1.5005x over previous
//
#include <hip/hip_runtime.h>

#define DI __device__ __forceinline__

typedef __attribute__((ext_vector_type(4))) float f32x4;
typedef __attribute__((ext_vector_type(8))) short short8;
typedef __attribute__((ext_vector_type(4))) short s16x4;
typedef unsigned short u16;
typedef unsigned long long u64;

#define GLDS(gp, lp)                                              \
  __builtin_amdgcn_global_load_lds(                               \
      (const __attribute__((address_space(1))) void*)(gp),        \
      (__attribute__((address_space(3))) void*)(lp), 16, 0, 0)

DI u16 f2bf(float f) {
  unsigned u = __builtin_bit_cast(unsigned, f);
  u += 0x7fffu + ((u >> 16) & 1u);
  return (u16)(u >> 16);
}
DI float bf2f(u16 h) {
  unsigned u = ((unsigned)h) << 16;
  return __builtin_bit_cast(float, u);
}

// ---------------------------------------------------------------------------
// GEMM: C = epilogue(A[.,lda] * B[.,ldb]^T), ALL bf16 operands.
// global_load_lds staging (linear LDS dest, inverse-swizzled global source,
// XOR-swizzled ds_read), double-buffered, one __syncthreads per K-step.
// MODE 0: fp32 out = acc (split-K partial)        -> Cp + z*sC + m*N + n
// MODE 1: bf16 out = relu(acc + bias[n])          -> Cp + m*N + n
// MODE 2: QKV weights at Bp + z*sB; z selects A (q vs kv) and out:
//         z=0 -> q scatter, z=1 -> k scatter [((b*16+h)*1024+t)*64+d],
//         z=2 -> V^T direct: LDS-transposed epilogue -> vt[bh][d][1024 t]
// ---------------------------------------------------------------------------
template <int MODE>
__global__ __launch_bounds__(256, 2) void gemm_bt(
    const u16* __restrict__ Ap, const u16* __restrict__ Ap2,
    const u16* __restrict__ Bp, void* __restrict__ Cp, void* __restrict__ Cp2,
    void* __restrict__ Cp3, const float* __restrict__ bias, int N, int lda,
    int ldb, int kz, int NT, long sB, long sC, float scale) {
  constexpr int BM = 128, BN = 128;
  constexpr int WM = BM / 2, WN = BN / 2, FM = WM / 16, FN = WN / 16;
  constexpr int ATILE = BM * 128, TILE = ATILE + BN * 128;

  __shared__ char smem[2 * TILE];

  const int tid = threadIdx.x;
  const int wid = tid >> 6, lane = tid & 63;
  const int z = blockIdx.z;
  const long bm = (long)blockIdx.y * BM;
  const long bn = (long)blockIdx.x * BN;
  const int kofs = z * kz;

  const u16* A16 = (MODE == 2 && z > 0) ? Ap2 : Ap;
  const u16* B16 = Bp + (long)z * sB;

  const int lrow = lane >> 3;
  const int lslot = (lane & 7) ^ lrow;
  const u16* asrc0 = A16 + (bm + lrow) * (long)lda + kofs + lslot * 8;
  const u16* bsrc0 = B16 + (bn + lrow) * (long)ldb + kofs + lslot * 8;

  auto stage = [&](int kt, char* buf) {
    const u16* as = asrc0 + kt * 64;
    const u16* bs = bsrc0 + kt * 64;
#pragma unroll
    for (int c = 0; c < 4; c++) {
      int chunk = wid * 4 + c;
      GLDS(as + (long)chunk * 8 * lda, buf + chunk * 1024);
    }
#pragma unroll
    for (int c = 0; c < 4; c++) {
      int chunk = wid * 4 + c;
      GLDS(bs + (long)chunk * 8 * ldb, buf + ATILE + chunk * 1024);
    }
  };

  const int wm = wid >> 1, wn = wid & 1;
  const int l15 = lane & 15, ks = lane >> 4;

  f32x4 acc[FM][FN];
#pragma unroll
  for (int i = 0; i < FM; i++)
#pragma unroll
    for (int j = 0; j < FN; j++) acc[i][j] = (f32x4){0.f, 0.f, 0.f, 0.f};

  auto compute = [&](const char* buf) {
    const char* As = buf;
    const char* Bs = buf + ATILE;
#pragma unroll
    for (int kk = 0; kk < 2; kk++) {
      short8 af[FM], bfr[FN];
#pragma unroll
      for (int i = 0; i < FM; i++) {
        int row = wm * WM + i * 16 + l15;
        int byte = row * 128 + kk * 64 + ks * 16;
        byte ^= (row & 7) << 4;
        af[i] = *(const short8*)(As + byte);
      }
#pragma unroll
      for (int j = 0; j < FN; j++) {
        int row = wn * WN + j * 16 + l15;
        int byte = row * 128 + kk * 64 + ks * 16;
        byte ^= (row & 7) << 4;
        bfr[j] = *(const short8*)(Bs + byte);
      }
#pragma unroll
      for (int i = 0; i < FM; i++)
#pragma unroll
        for (int j = 0; j < FN; j++)
          acc[i][j] = __builtin_amdgcn_mfma_f32_16x16x32_bf16(af[i], bfr[j],
                                                              acc[i][j], 0, 0, 0);
    }
  };

  stage(0, smem);
  __syncthreads();
  for (int t = 0; t < NT; ++t) {
    char* cur = smem + (t & 1) * TILE;
    char* nxt = smem + ((t + 1) & 1) * TILE;
    if (t + 1 < NT) stage(t + 1, nxt);
    compute(cur);
    __syncthreads();
  }

  if constexpr (MODE == 2) {
    if (z == 2) {
      // V^T epilogue: acc -> LDS transposed [n'][even m | odd m] -> vt
      char* tb = smem;
#pragma unroll
      for (int i = 0; i < FM; i++) {
#pragma unroll
        for (int j = 0; j < FN; j++) {
          int np = wn * 64 + j * 16 + l15;
          int basem = wm * 64 + i * 16 + ks * 4;
          unsigned lo = (unsigned)f2bf(acc[i][j][0]) |
                        ((unsigned)f2bf(acc[i][j][2]) << 16);
          unsigned hi = (unsigned)f2bf(acc[i][j][1]) |
                        ((unsigned)f2bf(acc[i][j][3]) << 16);
          int byte0 = np * 256 + basem;
          int byte1 = np * 256 + 128 + basem;
          byte0 ^= (np & 7) << 4;
          byte1 ^= (np & 7) << 4;
          *(unsigned*)(tb + byte0) = lo;
          *(unsigned*)(tb + byte1) = hi;
        }
      }
      __syncthreads();
      const int np = tid >> 1, bsel = tid & 1;
      const int h_ = (int)((bn + np) >> 6), d_ = (int)((bn + np) & 63);
      u16* dst = (u16*)Cp3 + ((long)(bsel * 16 + h_) * 64 + d_) * 1024 +
                 (bm >> 1);
#pragma unroll
      for (int c = 0; c < 8; c++) {
        int byte = np * 256 + bsel * 128 + c * 16;
        byte ^= (np & 7) << 4;
        *(short8*)(dst + c * 8) = *(const short8*)(tb + byte);
      }
      return;
    }
  }

  const float scl = (MODE == 2 && z > 0) ? 1.f : scale;
#pragma unroll
  for (int i = 0; i < FM; i++) {
#pragma unroll
    for (int j = 0; j < FN; j++) {
#pragma unroll
      for (int r = 0; r < 4; r++) {
        long m = bm + wm * WM + i * 16 + ks * 4 + r;
        long n = bn + wn * WN + j * 16 + l15;
        float val = acc[i][j][r] * scl;
        if constexpr (MODE == 0) {
          ((float*)Cp)[z * sC + m * (long)N + n] = val;
        } else if constexpr (MODE == 1) {
          val += bias[n];
          ((u16*)Cp)[m * (long)N + n] = f2bf(fmaxf(val, 0.f));
        } else if constexpr (MODE == 2) {
          u16* Cz = (u16*)(z == 0 ? Cp : Cp2);
          long t_ = m >> 1;
          int b_ = (int)(m & 1), h_ = (int)(n >> 6), d_ = (int)(n & 63);
          Cz[(((long)(b_ * 16 + h_) * 1024 + t_) << 6) + d_] = f2bf(val);
        }
      }
    }
  }
}

// ---------------------------------------------------------------------------
// weight cast: fp32 matrices (selected by blockIdx.y) -> bf16 at out + y*per
// ---------------------------------------------------------------------------
__global__ __launch_bounds__(256) void castw_k(const float* __restrict__ a,
                                               const float* __restrict__ b,
                                               const float* __restrict__ c,
                                               const float* __restrict__ d,
                                               u16* __restrict__ out,
                                               long per) {
  const int y = blockIdx.y;
  const float* s = y == 0 ? a : (y == 1 ? b : (y == 2 ? c : d));
  const long i = ((long)blockIdx.x * 256 + threadIdx.x) * 4;
  f32x4 v = *(const f32x4*)(s + i);
  s16x4 hh;
#pragma unroll
  for (int j = 0; j < 4; j++) hh[j] = (short)f2bf(v[j]);
  *(s16x4*)(out + y * per + i) = hh;
}

// ---------------------------------------------------------------------------
// Flash attention: block = 64 q rows x one (b,h); 4 waves x 16 q rows.
// K/V tiles (KVBLK=64) staged in block-shared LDS via global_load_lds,
// double-buffered, one barrier per tile. P staging is wave-local LDS.
// ---------------------------------------------------------------------------
__global__ __launch_bounds__(256, 2) void flash_k(
    const u16* __restrict__ q, const u16* __restrict__ kb,
    const u16* __restrict__ vt, u16* __restrict__ ab) {
  __shared__ char Ks[2][8192];       // [kv 64][d 64] bf16, XOR-swizzled
  __shared__ char Vs[2][8192];       // [d 64][kv 64] bf16, XOR-swizzled
  __shared__ char P_lds[4][2048];    // per wave: 16 q x 64 kv bf16
  __shared__ float stats[4][16];

  const int tid = threadIdx.x;
  const int wid = tid >> 6, lane = tid & 63;
  const int l15 = lane & 15, ks = lane >> 4;
  const int z = blockIdx.y;
  const int q0 = blockIdx.x * 64 + wid * 16;

  const u16* Qz = q + (long)z * 65536;
  const u16* Kz = kb + (long)z * 65536;
  const u16* Vz = vt + (long)z * 65536;
  char* Pw = P_lds[wid];
  float* st = stats[wid];

  const int r_l = lane >> 3;
  const int swsl = ((lane & 7) ^ r_l) * 8;

  auto stageKV = [&](int t, int buf) {
    const int kv0 = t * 64;
#pragma unroll
    for (int c = 0; c < 2; c++) {
      int chunk = wid * 2 + c;
      GLDS(Kz + (long)(kv0 + chunk * 8 + r_l) * 64 + swsl,
           Ks[buf] + chunk * 1024);
      GLDS(Vz + (long)(chunk * 8 + r_l) * 1024 + kv0 + swsl,
           Vs[buf] + chunk * 1024);
    }
  };

  short8 qf[2];
#pragma unroll
  for (int kk = 0; kk < 2; kk++)
    qf[kk] = *(const short8*)(Qz + (q0 + l15) * 64 + kk * 32 + ks * 8);

  f32x4 Oacc[4];
#pragma unroll
  for (int nf = 0; nf < 4; nf++) Oacc[nf] = (f32x4){0.f, 0.f, 0.f, 0.f};
  float mrun = -1e30f, lrun = 0.f;

  stageKV(0, 0);
  __syncthreads();
  for (int t = 0; t < 16; ++t) {
    const int cur = t & 1;
    if (t + 1 < 16) stageKV(t + 1, cur ^ 1);
    f32x4 s[4];
#pragma unroll
    for (int m = 0; m < 4; m++) s[m] = (f32x4){0.f, 0.f, 0.f, 0.f};
#pragma unroll
    for (int kk = 0; kk < 2; kk++) {
#pragma unroll
      for (int m = 0; m < 4; m++) {
        int row = m * 16 + l15;
        int byte = row * 128 + kk * 64 + ks * 16;
        byte ^= (row & 7) << 4;
        short8 kf = *(const short8*)(Ks[cur] + byte);
        s[m] = __builtin_amdgcn_mfma_f32_16x16x32_bf16(kf, qf[kk], s[m], 0, 0, 0);
      }
    }
    float tmax = s[0][0];
#pragma unroll
    for (int m = 0; m < 4; m++)
#pragma unroll
      for (int r = 0; r < 4; r++) tmax = fmaxf(tmax, s[m][r]);
    tmax = fmaxf(tmax, __shfl_xor(tmax, 16));
    tmax = fmaxf(tmax, __shfl_xor(tmax, 32));
    const float mnew = fmaxf(mrun, tmax);
    const float factor = __expf(mrun - mnew);
    float psum = 0.f;
#pragma unroll
    for (int m = 0; m < 4; m++) {
      u16 p4[4];
#pragma unroll
      for (int r = 0; r < 4; r++) {
        float e = __expf(s[m][r] - mnew);
        psum += e;
        p4[r] = f2bf(e);
      }
      u64 pk = (u64)p4[0] | ((u64)p4[1] << 16) | ((u64)p4[2] << 32) |
               ((u64)p4[3] << 48);
      int byte = l15 * 128 + m * 32 + ks * 8;
      byte ^= (l15 & 7) << 4;
      *(u64*)(Pw + byte) = pk;
    }
    psum += __shfl_xor(psum, 16);
    psum += __shfl_xor(psum, 32);
    lrun = lrun * factor + psum;
    mrun = mnew;
    if (ks == 0) st[l15] = factor;
    f32x4 facv = *(const f32x4*)&st[ks * 4];
#pragma unroll
    for (int nf = 0; nf < 4; nf++)
#pragma unroll
      for (int r = 0; r < 4; r++) Oacc[nf][r] *= facv[r];
#pragma unroll
    for (int kk = 0; kk < 2; kk++) {
      int pb = l15 * 128 + kk * 64 + ks * 16;
      pb ^= (l15 & 7) << 4;
      short8 pa = *(const short8*)(Pw + pb);
#pragma unroll
      for (int nf = 0; nf < 4; nf++) {
        int row = nf * 16 + l15;
        int vb_ = row * 128 + kk * 64 + ks * 16;
        vb_ ^= (row & 7) << 4;
        short8 vf = *(const short8*)(Vs[cur] + vb_);
        Oacc[nf] = __builtin_amdgcn_mfma_f32_16x16x32_bf16(pa, vf, Oacc[nf],
                                                           0, 0, 0);
      }
    }
    __syncthreads();
  }
  if (ks == 0) st[l15] = 1.f / lrun;
  f32x4 invv = *(const f32x4*)&st[ks * 4];
  const int b_ = z >> 4, h_ = z & 15;
#pragma unroll
  for (int nf = 0; nf < 4; nf++) {
#pragma unroll
    for (int r = 0; r < 4; r++) {
      int qg = q0 + ks * 4 + r;
      ab[((long)(qg * 2 + b_) << 10) + h_ * 64 + nf * 16 + l15] =
          f2bf(Oacc[nf][r] * invv[r]);
    }
  }
}

// ---------------------------------------------------------------------------
// out = LN(x + sum(parts) + cb) * g + b ; writes fp32 out and optional bf16
// ---------------------------------------------------------------------------
template <int NP>
__global__ __launch_bounds__(256) void add_ln_k(
    const float* __restrict__ x, const float* __restrict__ parts,
    const float* __restrict__ cb, const float* __restrict__ g,
    const float* __restrict__ b, float* __restrict__ out,
    u16* __restrict__ outh) {
  const long row = blockIdx.x;
  const int tid = threadIdx.x;
  const long base = row * 1024 + tid * 4;
  f32x4 v = *(const f32x4*)(x + base);
#pragma unroll
  for (int p = 0; p < NP; p++) {
    f32x4 q = *(const f32x4*)(parts + (long)p * 2048 * 1024 + base);
    v[0] += q[0]; v[1] += q[1]; v[2] += q[2]; v[3] += q[3];
  }
  if (cb) {
    f32x4 q = *(const f32x4*)(cb + tid * 4);
    v[0] += q[0]; v[1] += q[1]; v[2] += q[2]; v[3] += q[3];
  }
  float s = v[0] + v[1] + v[2] + v[3];
  float s2 = v[0] * v[0] + v[1] * v[1] + v[2] * v[2] + v[3] * v[3];
#pragma unroll
  for (int off = 1; off < 64; off <<= 1) {
    s += __shfl_xor(s, off);
    s2 += __shfl_xor(s2, off);
  }
  __shared__ float ps[8];
  const int wid = tid >> 6, lane = tid & 63;
  if (lane == 0) {
    ps[wid] = s;
    ps[4 + wid] = s2;
  }
  __syncthreads();
  s = ps[0] + ps[1] + ps[2] + ps[3];
  s2 = ps[4] + ps[5] + ps[6] + ps[7];
  float mean = s * (1.f / 1024.f);
  float var = s2 * (1.f / 1024.f) - mean * mean;
  float rstd = rsqrtf(var + 1e-5f);
  f32x4 gg = *(const f32x4*)(g + tid * 4);
  f32x4 bb = *(const f32x4*)(b + tid * 4);
  f32x4 o;
#pragma unroll
  for (int j = 0; j < 4; j++) o[j] = (v[j] - mean) * rstd * gg[j] + bb[j];
  *(f32x4*)(out + base) = o;
  if (outh) {
    s16x4 hh;
#pragma unroll
    for (int j = 0; j < 4; j++) hh[j] = (short)f2bf(o[j]);
    *(s16x4*)(outh + base) = hh;
  }
}

// fp32 -> (fp32 copy, bf16 copy)
__global__ __launch_bounds__(256) void cast_k(const float* __restrict__ in,
                                              float* __restrict__ o32,
                                              u16* __restrict__ o16) {
  const long i = ((long)blockIdx.x * 256 + threadIdx.x) * 4;
  f32x4 v = *(const f32x4*)(in + i);
  *(f32x4*)(o32 + i) = v;
  s16x4 hh;
#pragma unroll
  for (int j = 0; j < 4; j++) hh[j] = (short)f2bf(v[j]);
  *(s16x4*)(o16 + i) = hh;
}

// ---------------------------------------------------------------------------
extern "C" void kernel_launch(void* const* d_in, const int* in_sizes, int n_in,
                              void* d_out, int out_size, void* d_ws,
                              size_t ws_size, hipStream_t stream) {
  const float* src = (const float*)d_in[0];
  const float* tgt = (const float*)d_in[1];
  const float* enc_Wq = (const float*)d_in[2];
  const float* enc_Wk = (const float*)d_in[3];
  const float* enc_Wv = (const float*)d_in[4];
  const float* enc_Wo = (const float*)d_in[5];
  const float* enc_bo = (const float*)d_in[6];
  const float* enc_ln1_g = (const float*)d_in[7];
  const float* enc_ln1_b = (const float*)d_in[8];
  const float* enc_W1 = (const float*)d_in[9];
  const float* enc_b1 = (const float*)d_in[10];
  const float* enc_W2 = (const float*)d_in[11];
  const float* enc_b2 = (const float*)d_in[12];
  const float* enc_ln2_g = (const float*)d_in[13];
  const float* enc_ln2_b = (const float*)d_in[14];
  const float* enc_fn_g = (const float*)d_in[15];
  const float* enc_fn_b = (const float*)d_in[16];
  const float* dec_sWq = (const float*)d_in[17];
  const float* dec_sWk = (const float*)d_in[18];
  const float* dec_sWv = (const float*)d_in[19];
  const float* dec_sWo = (const float*)d_in[20];
  const float* dec_sbo = (const float*)d_in[21];
  const float* dec_ln1_g = (const float*)d_in[22];
  const float* dec_ln1_b = (const float*)d_in[23];
  const float* dec_cWq = (const float*)d_in[24];
  const float* dec_cWk = (const float*)d_in[25];
  const float* dec_cWv = (const float*)d_in[26];
  const float* dec_cWo = (const float*)d_in[27];
  const float* dec_cbo = (const float*)d_in[28];
  const float* dec_ln2_g = (const float*)d_in[29];
  const float* dec_ln2_b = (const float*)d_in[30];
  const float* dec_W1 = (const float*)d_in[31];
  const float* dec_b1 = (const float*)d_in[32];
  const float* dec_W2 = (const float*)d_in[33];
  const float* dec_b2 = (const float*)d_in[34];
  const float* dec_ln3_g = (const float*)d_in[35];
  const float* dec_ln3_b = (const float*)d_in[36];
  const float* dec_fn_g = (const float*)d_in[37];
  const float* dec_fn_b = (const float*)d_in[38];

  char* ws = (char*)d_ws;
  size_t off = 0;
  auto alloc = [&](size_t bytes) {
    void* p = ws + off;
    off += (bytes + 255) & ~(size_t)255;
    return p;
  };
  float* xf = (float*)alloc(2048L * 1024 * 4);
  float* mem = (float*)alloc(2048L * 1024 * 4);
  u16* xh = (u16*)alloc(2048L * 1024 * 2);
  u16* memh = (u16*)alloc(2048L * 1024 * 2);
  u16* h = (u16*)alloc(2048L * 4096 * 2);
  u16* q = (u16*)alloc(2048L * 1024 * 2);
  u16* kb = (u16*)alloc(2048L * 1024 * 2);
  u16* vt = (u16*)alloc(2048L * 1024 * 2);
  u16* ab = (u16*)alloc(2048L * 1024 * 2);
  float* parts = (float*)alloc(4L * 2048 * 1024 * 4);
  u16* wbuf = (u16*)alloc(8L * 1024 * 1024 * 2);     // per-layer fallback
  u16* wbig = (u16*)alloc(112L * 1024 * 1024 * 2);   // all-weights bf16
  const bool mega = off <= ws_size;

  const long sP = 2048L * 1024;
  const long M1 = 1024L * 1024, M4 = 4L * 1024 * 1024;
  // wbig layout: encA[16M] encF[32M] decS[16M] decC[16M] decF[32M]
  u16* encA = wbig;
  u16* encF = wbig + 16 * M1;
  u16* decS = wbig + 48 * M1;
  u16* decC = wbig + 64 * M1;
  u16* decF = wbig + 80 * M1;

  if (mega) {
    castw_k<<<dim3(4096, 4), 256, 0, stream>>>(enc_Wq, enc_Wk, enc_Wv, enc_Wo,
                                               encA, 4 * M1);
    castw_k<<<dim3(16384, 2), 256, 0, stream>>>(enc_W1, enc_W2, enc_W1, enc_W1,
                                                encF, 16 * M1);
    castw_k<<<dim3(4096, 4), 256, 0, stream>>>(dec_sWq, dec_sWk, dec_sWv,
                                               dec_sWo, decS, 4 * M1);
    castw_k<<<dim3(4096, 4), 256, 0, stream>>>(dec_cWq, dec_cWk, dec_cWv,
                                               dec_cWo, decC, 4 * M1);
    castw_k<<<dim3(16384, 2), 256, 0, stream>>>(dec_W1, dec_W2, dec_W1, dec_W1,
                                                decF, 16 * M1);
  }

  auto attn = [&](const u16* qin, const u16* kvin, const float* Wq,
                  const float* Wk, const float* Wv, const float* Wo,
                  const u16* bqkv, long sBq, const u16* bo) {
    if (!mega) {
      castw_k<<<dim3(1024, 4), 256, 0, stream>>>(Wq, Wk, Wv, Wo, wbuf, M1);
      bqkv = wbuf; sBq = M1; bo = wbuf + 3 * M1;
    }
    // fused QKV projection (z: 0=Q, 1=K, 2=V^T-direct)
    gemm_bt<2><<<dim3(8, 16, 3), 256, 0, stream>>>(
        qin, kvin, bqkv, q, kb, vt, nullptr,
        1024, 1024, 1024, 0, 16, sBq, 0, 0.125f);
    flash_k<<<dim3(16, 32), 256, 0, stream>>>(q, kb, vt, ab);
    gemm_bt<0><<<dim3(8, 16, 2), 256, 0, stream>>>(
        ab, nullptr, bo, parts, nullptr, nullptr, nullptr,
        1024, 1024, 1024, 512, 8, 0, sP, 1.f);
  };
  auto ffn = [&](const u16* xin, const float* W1, const float* b1,
                 const float* W2, const u16* bw1, const u16* bw2) {
    if (!mega) {
      castw_k<<<dim3(4096, 2), 256, 0, stream>>>(W1, W2, W1, W1, wbuf, M4);
      bw1 = wbuf; bw2 = wbuf + M4;
    }
    gemm_bt<1><<<dim3(32, 16, 1), 256, 0, stream>>>(
        xin, nullptr, bw1, h, nullptr, nullptr, b1,
        4096, 1024, 1024, 0, 16, 0, 0, 1.f);
    gemm_bt<0><<<dim3(8, 16, 4), 256, 0, stream>>>(
        h, nullptr, bw2, parts, nullptr, nullptr, nullptr,
        1024, 4096, 4096, 1024, 16, 0, sP, 1.f);
  };

  const long DD = 1024L * 1024, Dv = 1024, FFD = 4096L * 1024, FFv = 4096;

  cast_k<<<dim3(2048), 256, 0, stream>>>(src, xf, xh);
  for (int i = 0; i < 4; i++) {
    attn(xh, xh, enc_Wq + i * DD, enc_Wk + i * DD, enc_Wv + i * DD,
         enc_Wo + i * DD, encA + i * M1, 4 * M1, encA + 12 * M1 + i * M1);
    add_ln_k<2><<<dim3(2048), 256, 0, stream>>>(
        xf, parts, enc_bo + i * Dv, enc_ln1_g + i * Dv, enc_ln1_b + i * Dv,
        xf, xh);
    ffn(xh, enc_W1 + i * FFD, enc_b1 + i * FFv, enc_W2 + i * FFD,
        encF + i * M4, encF + 16 * M1 + i * M4);
    add_ln_k<4><<<dim3(2048), 256, 0, stream>>>(
        xf, parts, enc_b2 + i * Dv, enc_ln2_g + i * Dv, enc_ln2_b + i * Dv,
        xf, xh);
  }
  add_ln_k<0><<<dim3(2048), 256, 0, stream>>>(
      xf, nullptr, nullptr, enc_fn_g, enc_fn_b, mem, memh);

  cast_k<<<dim3(2048), 256, 0, stream>>>(tgt, xf, xh);
  for (int i = 0; i < 4; i++) {
    attn(xh, xh, dec_sWq + i * DD, dec_sWk + i * DD, dec_sWv + i * DD,
         dec_sWo + i * DD, decS + i * M1, 4 * M1, decS + 12 * M1 + i * M1);
    add_ln_k<2><<<dim3(2048), 256, 0, stream>>>(
        xf, parts, dec_sbo + i * Dv, dec_ln1_g + i * Dv, dec_ln1_b + i * Dv,
        xf, xh);
    attn(xh, memh, dec_cWq + i * DD, dec_cWk + i * DD, dec_cWv + i * DD,
         dec_cWo + i * DD, decC + i * M1, 4 * M1, decC + 12 * M1 + i * M1);
    add_ln_k<2><<<dim3(2048), 256, 0, stream>>>(
        xf, parts, dec_cbo + i * Dv, dec_ln2_g + i * Dv, dec_ln2_b + i * Dv,
        xf, xh);
    ffn(xh, dec_W1 + i * FFD, dec_b1 + i * FFv, dec_W2 + i * FFD,
        decF + i * M4, decF + 16 * M1 + i * M4);
    add_ln_k<4><<<dim3(2048), 256, 0, stream>>>(
        xf, parts, dec_b2 + i * Dv, dec_ln3_g + i * Dv, dec_ln3_b + i * Dv,
        xf, xh);
  }
  add_ln_k<0><<<dim3(2048), 256, 0, stream>>>(
      xf, nullptr, nullptr, dec_fn_g, dec_fn_b, (float*)d_out, nullptr);
}

// Round 9
// 1438.060 us; speedup vs baseline: 1.5401x; 1.0264x over previous
//
#include <hip/hip_runtime.h>

#define DI __device__ __forceinline__

typedef __attribute__((ext_vector_type(4))) float f32x4;
typedef __attribute__((ext_vector_type(8))) short short8;
typedef __attribute__((ext_vector_type(4))) short s16x4;
typedef unsigned short u16;
typedef unsigned long long u64;

#define GLDS(gp, lp)                                              \
  __builtin_amdgcn_global_load_lds(                               \
      (const __attribute__((address_space(1))) void*)(gp),        \
      (__attribute__((address_space(3))) void*)(lp), 16, 0, 0)

DI u16 f2bf(float f) {
  unsigned u = __builtin_bit_cast(unsigned, f);
  u += 0x7fffu + ((u >> 16) & 1u);
  return (u16)(u >> 16);
}
DI float bf2f(u16 h) {
  unsigned u = ((unsigned)h) << 16;
  return __builtin_bit_cast(float, u);
}

// ---------------------------------------------------------------------------
// GEMM: C = epilogue(A[.,lda] * B[.,ldb]^T), ALL bf16 operands.
// global_load_lds staging (linear LDS dest, inverse-swizzled global source,
// XOR-swizzled ds_read), double-buffered, one __syncthreads per K-step.
// MODE 0: fp32 out = acc (split-K partial)        -> Cp + z*sC + m*N + n
// MODE 1: bf16 out = relu(acc + bias[n])          -> Cp + m*N + n
// MODE 2: QKV weights at Bp + z*sB; z selects A (q vs kv) and out:
//         z=0 -> q scatter, z=1 -> k scatter [((b*16+h)*1024+t)*64+d],
//         z=2 -> V^T direct: LDS-transposed epilogue -> vt[bh][d][1024 t]
// ---------------------------------------------------------------------------
template <int MODE>
__global__ __launch_bounds__(256, 2) void gemm_bt(
    const u16* __restrict__ Ap, const u16* __restrict__ Ap2,
    const u16* __restrict__ Bp, void* __restrict__ Cp, void* __restrict__ Cp2,
    void* __restrict__ Cp3, const float* __restrict__ bias, int N, int lda,
    int ldb, int kz, int NT, long sB, long sC, float scale) {
  constexpr int BM = 128, BN = 128;
  constexpr int WM = BM / 2, WN = BN / 2, FM = WM / 16, FN = WN / 16;
  constexpr int ATILE = BM * 128, TILE = ATILE + BN * 128;

  __shared__ char smem[2 * TILE];

  const int tid = threadIdx.x;
  const int wid = tid >> 6, lane = tid & 63;
  const int z = blockIdx.z;
  const long bm = (long)blockIdx.y * BM;
  const long bn = (long)blockIdx.x * BN;
  const int kofs = z * kz;

  const u16* A16 = (MODE == 2 && z > 0) ? Ap2 : Ap;
  const u16* B16 = Bp + (long)z * sB;

  const int lrow = lane >> 3;
  const int lslot = (lane & 7) ^ lrow;
  const u16* asrc0 = A16 + (bm + lrow) * (long)lda + kofs + lslot * 8;
  const u16* bsrc0 = B16 + (bn + lrow) * (long)ldb + kofs + lslot * 8;

  auto stage = [&](int kt, char* buf) {
    const u16* as = asrc0 + kt * 64;
    const u16* bs = bsrc0 + kt * 64;
#pragma unroll
    for (int c = 0; c < 4; c++) {
      int chunk = wid * 4 + c;
      GLDS(as + (long)chunk * 8 * lda, buf + chunk * 1024);
    }
#pragma unroll
    for (int c = 0; c < 4; c++) {
      int chunk = wid * 4 + c;
      GLDS(bs + (long)chunk * 8 * ldb, buf + ATILE + chunk * 1024);
    }
  };

  const int wm = wid >> 1, wn = wid & 1;
  const int l15 = lane & 15, ks = lane >> 4;

  f32x4 acc[FM][FN];
#pragma unroll
  for (int i = 0; i < FM; i++)
#pragma unroll
    for (int j = 0; j < FN; j++) acc[i][j] = (f32x4){0.f, 0.f, 0.f, 0.f};

  auto compute = [&](const char* buf) {
    const char* As = buf;
    const char* Bs = buf + ATILE;
#pragma unroll
    for (int kk = 0; kk < 2; kk++) {
      short8 af[FM], bfr[FN];
#pragma unroll
      for (int i = 0; i < FM; i++) {
        int row = wm * WM + i * 16 + l15;
        int byte = row * 128 + kk * 64 + ks * 16;
        byte ^= (row & 7) << 4;
        af[i] = *(const short8*)(As + byte);
      }
#pragma unroll
      for (int j = 0; j < FN; j++) {
        int row = wn * WN + j * 16 + l15;
        int byte = row * 128 + kk * 64 + ks * 16;
        byte ^= (row & 7) << 4;
        bfr[j] = *(const short8*)(Bs + byte);
      }
#pragma unroll
      for (int i = 0; i < FM; i++)
#pragma unroll
        for (int j = 0; j < FN; j++)
          acc[i][j] = __builtin_amdgcn_mfma_f32_16x16x32_bf16(af[i], bfr[j],
                                                              acc[i][j], 0, 0, 0);
    }
  };

  stage(0, smem);
  __syncthreads();
  for (int t = 0; t < NT; ++t) {
    char* cur = smem + (t & 1) * TILE;
    char* nxt = smem + ((t + 1) & 1) * TILE;
    if (t + 1 < NT) stage(t + 1, nxt);
    compute(cur);
    __syncthreads();
  }

  if constexpr (MODE == 2) {
    if (z == 2) {
      // V^T epilogue: acc -> LDS transposed [n'][even m | odd m] -> vt
      char* tb = smem;
#pragma unroll
      for (int i = 0; i < FM; i++) {
#pragma unroll
        for (int j = 0; j < FN; j++) {
          int np = wn * 64 + j * 16 + l15;
          int basem = wm * 64 + i * 16 + ks * 4;
          unsigned lo = (unsigned)f2bf(acc[i][j][0]) |
                        ((unsigned)f2bf(acc[i][j][2]) << 16);
          unsigned hi = (unsigned)f2bf(acc[i][j][1]) |
                        ((unsigned)f2bf(acc[i][j][3]) << 16);
          int byte0 = np * 256 + basem;
          int byte1 = np * 256 + 128 + basem;
          byte0 ^= (np & 7) << 4;
          byte1 ^= (np & 7) << 4;
          *(unsigned*)(tb + byte0) = lo;
          *(unsigned*)(tb + byte1) = hi;
        }
      }
      __syncthreads();
      const int np = tid >> 1, bsel = tid & 1;
      const int h_ = (int)((bn + np) >> 6), d_ = (int)((bn + np) & 63);
      u16* dst = (u16*)Cp3 + ((long)(bsel * 16 + h_) * 64 + d_) * 1024 +
                 (bm >> 1);
#pragma unroll
      for (int c = 0; c < 8; c++) {
        int byte = np * 256 + bsel * 128 + c * 16;
        byte ^= (np & 7) << 4;
        *(short8*)(dst + c * 8) = *(const short8*)(tb + byte);
      }
      return;
    }
  }

  const float scl = (MODE == 2 && z > 0) ? 1.f : scale;
#pragma unroll
  for (int i = 0; i < FM; i++) {
#pragma unroll
    for (int j = 0; j < FN; j++) {
#pragma unroll
      for (int r = 0; r < 4; r++) {
        long m = bm + wm * WM + i * 16 + ks * 4 + r;
        long n = bn + wn * WN + j * 16 + l15;
        float val = acc[i][j][r] * scl;
        if constexpr (MODE == 0) {
          ((float*)Cp)[z * sC + m * (long)N + n] = val;
        } else if constexpr (MODE == 1) {
          val += bias[n];
          ((u16*)Cp)[m * (long)N + n] = f2bf(fmaxf(val, 0.f));
        } else if constexpr (MODE == 2) {
          u16* Cz = (u16*)(z == 0 ? Cp : Cp2);
          long t_ = m >> 1;
          int b_ = (int)(m & 1), h_ = (int)(n >> 6), d_ = (int)(n & 63);
          Cz[(((long)(b_ * 16 + h_) * 1024 + t_) << 6) + d_] = f2bf(val);
        }
      }
    }
  }
}

// ---------------------------------------------------------------------------
// weight cast: fp32 matrices (selected by blockIdx.y) -> bf16 at out + y*per
// ---------------------------------------------------------------------------
__global__ __launch_bounds__(256) void castw_k(const float* __restrict__ a,
                                               const float* __restrict__ b,
                                               const float* __restrict__ c,
                                               const float* __restrict__ d,
                                               u16* __restrict__ out,
                                               long per) {
  const int y = blockIdx.y;
  const float* s = y == 0 ? a : (y == 1 ? b : (y == 2 ? c : d));
  const long i = ((long)blockIdx.x * 256 + threadIdx.x) * 4;
  f32x4 v = *(const f32x4*)(s + i);
  s16x4 hh;
#pragma unroll
  for (int j = 0; j < 4; j++) hh[j] = (short)f2bf(v[j]);
  *(s16x4*)(out + y * per + i) = hh;
}

// ---------------------------------------------------------------------------
// Flash attention: block = 64 q rows x one (b,h); 4 waves x 16 q rows.
// K/V tiles (KVBLK=64) staged in block-shared LDS via global_load_lds,
// double-buffered, one barrier per tile. P staging is wave-local LDS.
// ---------------------------------------------------------------------------
__global__ __launch_bounds__(256, 2) void flash_k(
    const u16* __restrict__ q, const u16* __restrict__ kb,
    const u16* __restrict__ vt, u16* __restrict__ ab) {
  __shared__ char Ks[2][8192];       // [kv 64][d 64] bf16, XOR-swizzled
  __shared__ char Vs[2][8192];       // [d 64][kv 64] bf16, XOR-swizzled
  __shared__ char P_lds[4][2048];    // per wave: 16 q x 64 kv bf16
  __shared__ float stats[4][16];

  const int tid = threadIdx.x;
  const int wid = tid >> 6, lane = tid & 63;
  const int l15 = lane & 15, ks = lane >> 4;
  const int z = blockIdx.y;
  const int q0 = blockIdx.x * 64 + wid * 16;

  const u16* Qz = q + (long)z * 65536;
  const u16* Kz = kb + (long)z * 65536;
  const u16* Vz = vt + (long)z * 65536;
  char* Pw = P_lds[wid];
  float* st = stats[wid];

  const int r_l = lane >> 3;
  const int swsl = ((lane & 7) ^ r_l) * 8;

  auto stageKV = [&](int t, int buf) {
    const int kv0 = t * 64;
#pragma unroll
    for (int c = 0; c < 2; c++) {
      int chunk = wid * 2 + c;
      GLDS(Kz + (long)(kv0 + chunk * 8 + r_l) * 64 + swsl,
           Ks[buf] + chunk * 1024);
      GLDS(Vz + (long)(chunk * 8 + r_l) * 1024 + kv0 + swsl,
           Vs[buf] + chunk * 1024);
    }
  };

  short8 qf[2];
#pragma unroll
  for (int kk = 0; kk < 2; kk++)
    qf[kk] = *(const short8*)(Qz + (q0 + l15) * 64 + kk * 32 + ks * 8);

  f32x4 Oacc[4];
#pragma unroll
  for (int nf = 0; nf < 4; nf++) Oacc[nf] = (f32x4){0.f, 0.f, 0.f, 0.f};
  float mrun = -1e30f, lrun = 0.f;

  stageKV(0, 0);
  __syncthreads();
  for (int t = 0; t < 16; ++t) {
    const int cur = t & 1;
    if (t + 1 < 16) stageKV(t + 1, cur ^ 1);
    f32x4 s[4];
#pragma unroll
    for (int m = 0; m < 4; m++) s[m] = (f32x4){0.f, 0.f, 0.f, 0.f};
#pragma unroll
    for (int kk = 0; kk < 2; kk++) {
#pragma unroll
      for (int m = 0; m < 4; m++) {
        int row = m * 16 + l15;
        int byte = row * 128 + kk * 64 + ks * 16;
        byte ^= (row & 7) << 4;
        short8 kf = *(const short8*)(Ks[cur] + byte);
        s[m] = __builtin_amdgcn_mfma_f32_16x16x32_bf16(kf, qf[kk], s[m], 0, 0, 0);
      }
    }
    float tmax = s[0][0];
#pragma unroll
    for (int m = 0; m < 4; m++)
#pragma unroll
      for (int r = 0; r < 4; r++) tmax = fmaxf(tmax, s[m][r]);
    tmax = fmaxf(tmax, __shfl_xor(tmax, 16));
    tmax = fmaxf(tmax, __shfl_xor(tmax, 32));
    const float mnew = fmaxf(mrun, tmax);
    const float factor = __expf(mrun - mnew);
    float psum = 0.f;
#pragma unroll
    for (int m = 0; m < 4; m++) {
      u16 p4[4];
#pragma unroll
      for (int r = 0; r < 4; r++) {
        float e = __expf(s[m][r] - mnew);
        psum += e;
        p4[r] = f2bf(e);
      }
      u64 pk = (u64)p4[0] | ((u64)p4[1] << 16) | ((u64)p4[2] << 32) |
               ((u64)p4[3] << 48);
      int byte = l15 * 128 + m * 32 + ks * 8;
      byte ^= (l15 & 7) << 4;
      *(u64*)(Pw + byte) = pk;
    }
    psum += __shfl_xor(psum, 16);
    psum += __shfl_xor(psum, 32);
    lrun = lrun * factor + psum;
    mrun = mnew;
    if (ks == 0) st[l15] = factor;
    f32x4 facv = *(const f32x4*)&st[ks * 4];
#pragma unroll
    for (int nf = 0; nf < 4; nf++)
#pragma unroll
      for (int r = 0; r < 4; r++) Oacc[nf][r] *= facv[r];
#pragma unroll
    for (int kk = 0; kk < 2; kk++) {
      int pb = l15 * 128 + kk * 64 + ks * 16;
      pb ^= (l15 & 7) << 4;
      short8 pa = *(const short8*)(Pw + pb);
#pragma unroll
      for (int nf = 0; nf < 4; nf++) {
        int row = nf * 16 + l15;
        int vb_ = row * 128 + kk * 64 + ks * 16;
        vb_ ^= (row & 7) << 4;
        short8 vf = *(const short8*)(Vs[cur] + vb_);
        Oacc[nf] = __builtin_amdgcn_mfma_f32_16x16x32_bf16(pa, vf, Oacc[nf],
                                                           0, 0, 0);
      }
    }
    __syncthreads();
  }
  if (ks == 0) st[l15] = 1.f / lrun;
  f32x4 invv = *(const f32x4*)&st[ks * 4];
  const int b_ = z >> 4, h_ = z & 15;
#pragma unroll
  for (int nf = 0; nf < 4; nf++) {
#pragma unroll
    for (int r = 0; r < 4; r++) {
      int qg = q0 + ks * 4 + r;
      ab[((long)(qg * 2 + b_) << 10) + h_ * 64 + nf * 16 + l15] =
          f2bf(Oacc[nf][r] * invv[r]);
    }
  }
}

// ---------------------------------------------------------------------------
// out = LN(bf16 x + sum(parts) + cb) * g + b ; bf16 out, optional fp32 out
// ---------------------------------------------------------------------------
template <int NP>
__global__ __launch_bounds__(256) void add_ln_k(
    const u16* __restrict__ x, const float* __restrict__ parts,
    const float* __restrict__ cb, const float* __restrict__ g,
    const float* __restrict__ b, u16* __restrict__ outh,
    float* __restrict__ outf) {
  const long row = blockIdx.x;
  const int tid = threadIdx.x;
  const long base = row * 1024 + tid * 4;
  s16x4 xh = *(const s16x4*)(x + base);
  f32x4 v;
#pragma unroll
  for (int j = 0; j < 4; j++) v[j] = bf2f((u16)xh[j]);
#pragma unroll
  for (int p = 0; p < NP; p++) {
    f32x4 q = *(const f32x4*)(parts + (long)p * 2048 * 1024 + base);
    v[0] += q[0]; v[1] += q[1]; v[2] += q[2]; v[3] += q[3];
  }
  if (cb) {
    f32x4 q = *(const f32x4*)(cb + tid * 4);
    v[0] += q[0]; v[1] += q[1]; v[2] += q[2]; v[3] += q[3];
  }
  float s = v[0] + v[1] + v[2] + v[3];
  float s2 = v[0] * v[0] + v[1] * v[1] + v[2] * v[2] + v[3] * v[3];
#pragma unroll
  for (int off = 1; off < 64; off <<= 1) {
    s += __shfl_xor(s, off);
    s2 += __shfl_xor(s2, off);
  }
  __shared__ float ps[8];
  const int wid = tid >> 6, lane = tid & 63;
  if (lane == 0) {
    ps[wid] = s;
    ps[4 + wid] = s2;
  }
  __syncthreads();
  s = ps[0] + ps[1] + ps[2] + ps[3];
  s2 = ps[4] + ps[5] + ps[6] + ps[7];
  float mean = s * (1.f / 1024.f);
  float var = s2 * (1.f / 1024.f) - mean * mean;
  float rstd = rsqrtf(var + 1e-5f);
  f32x4 gg = *(const f32x4*)(g + tid * 4);
  f32x4 bb = *(const f32x4*)(b + tid * 4);
  f32x4 o;
#pragma unroll
  for (int j = 0; j < 4; j++) o[j] = (v[j] - mean) * rstd * gg[j] + bb[j];
  s16x4 hh;
#pragma unroll
  for (int j = 0; j < 4; j++) hh[j] = (short)f2bf(o[j]);
  *(s16x4*)(outh + base) = hh;
  if (outf) *(f32x4*)(outf + base) = o;
}

// fp32 -> bf16
__global__ __launch_bounds__(256) void cast_k(const float* __restrict__ in,
                                              u16* __restrict__ o16) {
  const long i = ((long)blockIdx.x * 256 + threadIdx.x) * 4;
  f32x4 v = *(const f32x4*)(in + i);
  s16x4 hh;
#pragma unroll
  for (int j = 0; j < 4; j++) hh[j] = (short)f2bf(v[j]);
  *(s16x4*)(o16 + i) = hh;
}

// ---------------------------------------------------------------------------
extern "C" void kernel_launch(void* const* d_in, const int* in_sizes, int n_in,
                              void* d_out, int out_size, void* d_ws,
                              size_t ws_size, hipStream_t stream) {
  const float* src = (const float*)d_in[0];
  const float* tgt = (const float*)d_in[1];
  const float* enc_Wq = (const float*)d_in[2];
  const float* enc_Wk = (const float*)d_in[3];
  const float* enc_Wv = (const float*)d_in[4];
  const float* enc_Wo = (const float*)d_in[5];
  const float* enc_bo = (const float*)d_in[6];
  const float* enc_ln1_g = (const float*)d_in[7];
  const float* enc_ln1_b = (const float*)d_in[8];
  const float* enc_W1 = (const float*)d_in[9];
  const float* enc_b1 = (const float*)d_in[10];
  const float* enc_W2 = (const float*)d_in[11];
  const float* enc_b2 = (const float*)d_in[12];
  const float* enc_ln2_g = (const float*)d_in[13];
  const float* enc_ln2_b = (const float*)d_in[14];
  const float* enc_fn_g = (const float*)d_in[15];
  const float* enc_fn_b = (const float*)d_in[16];
  const float* dec_sWq = (const float*)d_in[17];
  const float* dec_sWk = (const float*)d_in[18];
  const float* dec_sWv = (const float*)d_in[19];
  const float* dec_sWo = (const float*)d_in[20];
  const float* dec_sbo = (const float*)d_in[21];
  const float* dec_ln1_g = (const float*)d_in[22];
  const float* dec_ln1_b = (const float*)d_in[23];
  const float* dec_cWq = (const float*)d_in[24];
  const float* dec_cWk = (const float*)d_in[25];
  const float* dec_cWv = (const float*)d_in[26];
  const float* dec_cWo = (const float*)d_in[27];
  const float* dec_cbo = (const float*)d_in[28];
  const float* dec_ln2_g = (const float*)d_in[29];
  const float* dec_ln2_b = (const float*)d_in[30];
  const float* dec_W1 = (const float*)d_in[31];
  const float* dec_b1 = (const float*)d_in[32];
  const float* dec_W2 = (const float*)d_in[33];
  const float* dec_b2 = (const float*)d_in[34];
  const float* dec_ln3_g = (const float*)d_in[35];
  const float* dec_ln3_b = (const float*)d_in[36];
  const float* dec_fn_g = (const float*)d_in[37];
  const float* dec_fn_b = (const float*)d_in[38];

  char* ws = (char*)d_ws;
  size_t off = 0;
  auto alloc = [&](size_t bytes) {
    void* p = ws + off;
    off += (bytes + 255) & ~(size_t)255;
    return p;
  };
  u16* xh = (u16*)alloc(2048L * 1024 * 2);
  u16* memh = (u16*)alloc(2048L * 1024 * 2);
  u16* h = (u16*)alloc(2048L * 4096 * 2);
  u16* q = (u16*)alloc(2048L * 1024 * 2);
  u16* kb = (u16*)alloc(2048L * 1024 * 2);
  u16* vt = (u16*)alloc(2048L * 1024 * 2);
  u16* ab = (u16*)alloc(2048L * 1024 * 2);
  float* parts = (float*)alloc(4L * 2048 * 1024 * 4);
  u16* wbuf = (u16*)alloc(8L * 1024 * 1024 * 2);     // per-layer fallback
  u16* wbig = (u16*)alloc(112L * 1024 * 1024 * 2);   // all-weights bf16
  const bool mega = off <= ws_size;

  const long sP = 2048L * 1024;
  const long M1 = 1024L * 1024, M4 = 4L * 1024 * 1024;
  // wbig layout: encA[16M] encF[32M] decS[16M] decC[16M] decF[32M]
  u16* encA = wbig;
  u16* encF = wbig + 16 * M1;
  u16* decS = wbig + 48 * M1;
  u16* decC = wbig + 64 * M1;
  u16* decF = wbig + 80 * M1;

  if (mega) {
    castw_k<<<dim3(4096, 4), 256, 0, stream>>>(enc_Wq, enc_Wk, enc_Wv, enc_Wo,
                                               encA, 4 * M1);
    castw_k<<<dim3(16384, 2), 256, 0, stream>>>(enc_W1, enc_W2, enc_W1, enc_W1,
                                                encF, 16 * M1);
    castw_k<<<dim3(4096, 4), 256, 0, stream>>>(dec_sWq, dec_sWk, dec_sWv,
                                               dec_sWo, decS, 4 * M1);
    castw_k<<<dim3(4096, 4), 256, 0, stream>>>(dec_cWq, dec_cWk, dec_cWv,
                                               dec_cWo, decC, 4 * M1);
    castw_k<<<dim3(16384, 2), 256, 0, stream>>>(dec_W1, dec_W2, dec_W1, dec_W1,
                                                decF, 16 * M1);
  }

  auto attn = [&](const u16* qin, const u16* kvin, const float* Wq,
                  const float* Wk, const float* Wv, const float* Wo,
                  const u16* bqkv, long sBq, const u16* bo) {
    if (!mega) {
      castw_k<<<dim3(1024, 4), 256, 0, stream>>>(Wq, Wk, Wv, Wo, wbuf, M1);
      bqkv = wbuf; sBq = M1; bo = wbuf + 3 * M1;
    }
    // fused QKV projection (z: 0=Q, 1=K, 2=V^T-direct)
    gemm_bt<2><<<dim3(8, 16, 3), 256, 0, stream>>>(
        qin, kvin, bqkv, q, kb, vt, nullptr,
        1024, 1024, 1024, 0, 16, sBq, 0, 0.125f);
    flash_k<<<dim3(16, 32), 256, 0, stream>>>(q, kb, vt, ab);
    // O projection, split-K=4 -> fp32 partials (grid 512 = 2 blocks/CU)
    gemm_bt<0><<<dim3(8, 16, 4), 256, 0, stream>>>(
        ab, nullptr, bo, parts, nullptr, nullptr, nullptr,
        1024, 1024, 1024, 256, 4, 0, sP, 1.f);
  };
  auto ffn = [&](const u16* xin, const float* W1, const float* b1,
                 const float* W2, const u16* bw1, const u16* bw2) {
    if (!mega) {
      castw_k<<<dim3(4096, 2), 256, 0, stream>>>(W1, W2, W1, W1, wbuf, M4);
      bw1 = wbuf; bw2 = wbuf + M4;
    }
    gemm_bt<1><<<dim3(32, 16, 1), 256, 0, stream>>>(
        xin, nullptr, bw1, h, nullptr, nullptr, b1,
        4096, 1024, 1024, 0, 16, 0, 0, 1.f);
    gemm_bt<0><<<dim3(8, 16, 4), 256, 0, stream>>>(
        h, nullptr, bw2, parts, nullptr, nullptr, nullptr,
        1024, 4096, 4096, 1024, 16, 0, sP, 1.f);
  };

  const long DD = 1024L * 1024, Dv = 1024, FFD = 4096L * 1024, FFv = 4096;

  cast_k<<<dim3(2048), 256, 0, stream>>>(src, xh);
  for (int i = 0; i < 4; i++) {
    attn(xh, xh, enc_Wq + i * DD, enc_Wk + i * DD, enc_Wv + i * DD,
         enc_Wo + i * DD, encA + i * M1, 4 * M1, encA + 12 * M1 + i * M1);
    add_ln_k<4><<<dim3(2048), 256, 0, stream>>>(
        xh, parts, enc_bo + i * Dv, enc_ln1_g + i * Dv, enc_ln1_b + i * Dv,
        xh, nullptr);
    ffn(xh, enc_W1 + i * FFD, enc_b1 + i * FFv, enc_W2 + i * FFD,
        encF + i * M4, encF + 16 * M1 + i * M4);
    add_ln_k<4><<<dim3(2048), 256, 0, stream>>>(
        xh, parts, enc_b2 + i * Dv, enc_ln2_g + i * Dv, enc_ln2_b + i * Dv,
        xh, nullptr);
  }
  add_ln_k<0><<<dim3(2048), 256, 0, stream>>>(
      xh, nullptr, nullptr, enc_fn_g, enc_fn_b, memh, nullptr);

  cast_k<<<dim3(2048), 256, 0, stream>>>(tgt, xh);
  for (int i = 0; i < 4; i++) {
    attn(xh, xh, dec_sWq + i * DD, dec_sWk + i * DD, dec_sWv + i * DD,
         dec_sWo + i * DD, decS + i * M1, 4 * M1, decS + 12 * M1 + i * M1);
    add_ln_k<4><<<dim3(2048), 256, 0, stream>>>(
        xh, parts, dec_sbo + i * Dv, dec_ln1_g + i * Dv, dec_ln1_b + i * Dv,
        xh, nullptr);
    attn(xh, memh, dec_cWq + i * DD, dec_cWk + i * DD, dec_cWv + i * DD,
         dec_cWo + i * DD, decC + i * M1, 4 * M1, decC + 12 * M1 + i * M1);
    add_ln_k<4><<<dim3(2048), 256, 0, stream>>>(
        xh, parts, dec_cbo + i * Dv, dec_ln2_g + i * Dv, dec_ln2_b + i * Dv,
        xh, nullptr);
    ffn(xh, dec_W1 + i * FFD, dec_b1 + i * FFv, dec_W2 + i * FFD,
        decF + i * M4, decF + 16 * M1 + i * M4);
    add_ln_k<4><<<dim3(2048), 256, 0, stream>>>(
        xh, parts, dec_b2 + i * Dv, dec_ln3_g + i * Dv, dec_ln3_b + i * Dv,
        xh, nullptr);
  }
  add_ln_k<0><<<dim3(2048), 256, 0, stream>>>(
      xh, nullptr, nullptr, dec_fn_g, dec_fn_b, xh, (float*)d_out);
}